// Round 1
// baseline (188.597 us; speedup 1.0000x reference)
//
#include <hip/hip_runtime.h>
#include <cmath>

// Shapes fixed by the reference: data [32,128,80,80] int32, scale 0.0625.
#define NB  32
#define NC  128
#define NHW 6400          // 80*80, contiguous per (b,c)
#define PIX 64            // pixels per block
#define TPB 256           // 16 "k" channel-groups x 16 pixel-quads

// Thread t: k = t>>4 owns channels {k, k+16, ..., k+112};
//           p4 = t&15 owns pixels {4*p4 .. 4*p4+3} (one int4/float4 per channel).
// All data lives in registers (8 x int4); LDS only for the two 256-entry LUTs
// and the 16-way per-pixel max/sum reductions.

__global__ __launch_bounds__(TPB) void qsoftmax_kernel(
    const int* __restrict__ data,
    const float* __restrict__ dscale,
    float* __restrict__ out) {
#pragma clang fp contract(off)
  __shared__ int   exp_tab[256];    // quantized exp as function of j = qmax - data
  __shared__ float recip_tab[256];  // quantized 1/v table, region (0.1, 250)
  __shared__ int4  red[16][16];     // [k][p4] partial max, then partial sum
  __shared__ int4  qmax_s[16];      // per-pixel-quad channel max
  __shared__ float4 rq_s[16];       // per-pixel-quad recip_q (as float)

  const int t  = threadIdx.x;
  const int k  = t >> 4;
  const int p4 = t & 15;

  const int blk  = blockIdx.x;
  const int b    = blk / (NHW / PIX);
  const int hw0  = (blk % (NHW / PIX)) * PIX;
  const int base4 = b * NC * (NHW / 4) + (hw0 >> 2);   // int4 index

  const float ds = dscale[0];  // 0.0625

  // ---- build LUTs: thread t builds entry t of each table ----
  {
    const float EXP_SCALE_F = (float)(2.0 / 65535.0);
    // x = (data - qmax) * ds for j = t  (d = -t), exactly as the reference's f32 math
    float x = (float)(-t) * ds;
    float e;
    if (x >= 0.0f) {
      // line region (0, 1): only j == 0 lands here (x == 0)
      float y0 = expf(0.0f), y1 = expf(1.0f);
      e = rintf((y0 + x * ((y1 - y0) / 1.0f)) / EXP_SCALE_F);
    } else if (x >= -10.0f) {
      // table region (-10, 0): xs = linspace(-10,0,256) in f32
      float delta = 10.0f / 255.0f;
      float idxf = rintf((x + 10.0f) * 25.5f);            // 255/(0-(-10)) = 25.5
      idxf = fminf(fmaxf(idxf, 0.0f), 255.0f);
      float xs = -10.0f + idxf * delta;
      e = rintf((float)exp((double)xs) / EXP_SCALE_F);    // correctly-rounded f32 exp
    } else {
      // table region (-20, -10): reachable x >= -15.9375, so always >= -20
      float delta = 10.0f / 255.0f;
      float idxf = rintf((x + 20.0f) * 25.5f);
      idxf = fminf(fmaxf(idxf, 0.0f), 255.0f);
      float xs = -20.0f + idxf * delta;
      e = rintf((float)exp((double)xs) / EXP_SCALE_F);
    }
    e = fminf(fmaxf(e, -32768.0f), 32767.0f);
    exp_tab[t] = (int)e;

    // recip table: xs = linspace(0.1, 250, 256) in f32; quant(1/xs)
    const float RECIP_SCALE_F = (float)((1.0 / 0.1) * 2.0 / 65535.0);
    float deltar = (250.0f - 0.1f) / 255.0f;
    float xs = 0.1f + (float)t * deltar;
    float r = rintf((1.0f / xs) / RECIP_SCALE_F);         // IEEE f32 divides
    r = fminf(fmaxf(r, -32768.0f), 32767.0f);
    recip_tab[t] = r;
  }

  // ---- load 8 channels x 4 pixels into registers (16B/lane, coalesced) ----
  int4 d[8];
  const int4* g4 = (const int4*)data;
#pragma unroll
  for (int i = 0; i < 8; ++i) {
    d[i] = g4[base4 + (16 * i + k) * (NHW / 4) + p4];
  }

  // ---- per-pixel max over this thread's 8 channels, then 16-way reduce ----
  int4 m = d[0];
#pragma unroll
  for (int i = 1; i < 8; ++i) {
    m.x = max(m.x, d[i].x); m.y = max(m.y, d[i].y);
    m.z = max(m.z, d[i].z); m.w = max(m.w, d[i].w);
  }
  red[k][p4] = m;
  __syncthreads();
  if (k == 0) {
    int4 q = red[0][p4];
#pragma unroll
    for (int kk = 1; kk < 16; ++kk) {
      int4 r = red[kk][p4];
      q.x = max(q.x, r.x); q.y = max(q.y, r.y);
      q.z = max(q.z, r.z); q.w = max(q.w, r.w);
    }
    qmax_s[p4] = q;
  }
  __syncthreads();

  // ---- exp LUT + channel sum (exact integer sum, matches f32 exact sum) ----
  const int4 q = qmax_s[p4];
  int4 s = make_int4(0, 0, 0, 0);
#pragma unroll
  for (int i = 0; i < 8; ++i) {
    int4 v = d[i];
    int e0 = exp_tab[min(q.x - v.x, 255)];
    int e1 = exp_tab[min(q.y - v.y, 255)];
    int e2 = exp_tab[min(q.z - v.z, 255)];
    int e3 = exp_tab[min(q.w - v.w, 255)];
    s.x += e0; s.y += e1; s.z += e2; s.w += e3;
    d[i] = make_int4(e0, e1, e2, e3);   // keep exp_q in registers for the epilogue
  }
  red[k][p4] = s;
  __syncthreads();
  if (k == 0) {
    int4 tot = red[0][p4];
#pragma unroll
    for (int kk = 1; kk < 16; ++kk) {
      int4 r = red[kk][p4];
      tot.x += r.x; tot.y += r.y; tot.z += r.z; tot.w += r.w;
    }
    const float DIV_SCALE_F = (float)((2.0 / 65535.0) * 128.0); // exp_scale * 2^7
    const float RIDX_K_F    = (float)(255.0 / (250.0 - 0.1));
    auto recip_of = [&](int total) -> float {
      // sum_sh = clip(round(sum * 2^-7)); v = sum_sh * div_scale; table idx
      float ss = rintf((float)total * 0.0078125f);
      ss = fminf(fmaxf(ss, -32768.0f), 32767.0f);
      float v = ss * DIV_SCALE_F;
      float idxf = rintf((v - 0.1f) * RIDX_K_F);
      idxf = fminf(fmaxf(idxf, 0.0f), 255.0f);
      return recip_tab[(int)idxf];
    };
    float4 rq;
    rq.x = recip_of(tot.x);
    rq.y = recip_of(tot.y);
    rq.z = recip_of(tot.z);
    rq.w = recip_of(tot.w);
    rq_s[p4] = rq;
  }
  __syncthreads();

  // ---- epilogue: out = clip(round((e*r)*K), -128, 127) * OUT_SCALE ----
  const float4 rq = rq_s[p4];
  const float K_F = (float)((2.0 / 65535.0) * ((1.0 / 0.1) * 2.0 / 65535.0) / (2.0 / 255.0));
  const float OUT_SCALE_F = (float)(2.0 / 255.0);
  float4* o4 = (float4*)out;
#pragma unroll
  for (int i = 0; i < 8; ++i) {
    float4 o;
    o.x = fminf(fmaxf(rintf(((float)d[i].x * rq.x) * K_F), -128.0f), 127.0f) * OUT_SCALE_F;
    o.y = fminf(fmaxf(rintf(((float)d[i].y * rq.y) * K_F), -128.0f), 127.0f) * OUT_SCALE_F;
    o.z = fminf(fmaxf(rintf(((float)d[i].z * rq.z) * K_F), -128.0f), 127.0f) * OUT_SCALE_F;
    o.w = fminf(fmaxf(rintf(((float)d[i].w * rq.w) * K_F), -128.0f), 127.0f) * OUT_SCALE_F;
    o4[base4 + (16 * i + k) * (NHW / 4) + p4] = o;
  }
}

extern "C" void kernel_launch(void* const* d_in, const int* in_sizes, int n_in,
                              void* d_out, int out_size, void* d_ws, size_t ws_size,
                              hipStream_t stream) {
  const int* data     = (const int*)d_in[0];
  const float* dscale = (const float*)d_in[1];
  float* out          = (float*)d_out;
  (void)in_sizes; (void)n_in; (void)d_ws; (void)ws_size; (void)out_size;

  dim3 grid(NB * (NHW / PIX));   // 32 * 100 = 3200 blocks
  qsoftmax_kernel<<<grid, TPB, 0, stream>>>(data, dscale, out);
}

// Round 3
// 187.764 us; speedup vs baseline: 1.0044x; 1.0044x over previous
//
#include <hip/hip_runtime.h>
#include <cmath>

// Shapes fixed by the reference: data [32,128,80,80] int32, scale 0.0625.
#define NB  32
#define NC  128
#define NHW 6400          // 80*80, contiguous per (b,c)
#define PIX 64            // pixels per block
#define TPB 256           // 16 "k" channel-groups x 16 pixel-quads

typedef float vfloat4 __attribute__((ext_vector_type(4)));  // native vec for NT store

// Thread t: k = t>>4 owns channels {k, k+16, ..., k+112};
//           p4 = t&15 owns pixels {4*p4 .. 4*p4+3} (one int4/float4 per channel).
// Payload is PACKED: raw data 4x int8 per int (8 VGPRs), exp 2x u16 per int
// (16 VGPRs). Reductions: every thread redundantly reduces 16 partials from
// LDS (broadcast reads) -> only 2 barriers, no single-thread serial section.

__global__ __launch_bounds__(TPB) void qsoftmax_kernel(
    const int* __restrict__ data,
    const float* __restrict__ dscale,
    float* __restrict__ out) {
#pragma clang fp contract(off)
  __shared__ int   exp_tab[256];    // quantized exp as function of j = qmax - data
  __shared__ float recip_tab[256];  // quantized 1/v table, region (0.1, 250)
  __shared__ int4  red_m[16][16];   // [k][p4] partial max
  __shared__ int4  red_s[16][16];   // [k][p4] partial sum

  const int t  = threadIdx.x;
  const int k  = t >> 4;
  const int p4 = t & 15;

  const int blk  = blockIdx.x;
  const int b    = blk / (NHW / PIX);
  const int hw0  = (blk % (NHW / PIX)) * PIX;
  const int base4 = b * NC * (NHW / 4) + (hw0 >> 2);   // int4 index

  const float ds = dscale[0];  // 0.0625

  // ---- build LUTs (identical math to the absmax=0 version; do not touch) ----
  {
    const float EXP_SCALE_F = (float)(2.0 / 65535.0);
    float x = (float)(-t) * ds;
    float e;
    if (x >= 0.0f) {
      float y0 = expf(0.0f), y1 = expf(1.0f);
      e = rintf((y0 + x * ((y1 - y0) / 1.0f)) / EXP_SCALE_F);
    } else if (x >= -10.0f) {
      float delta = 10.0f / 255.0f;
      float idxf = rintf((x + 10.0f) * 25.5f);
      idxf = fminf(fmaxf(idxf, 0.0f), 255.0f);
      float xs = -10.0f + idxf * delta;
      e = rintf((float)exp((double)xs) / EXP_SCALE_F);
    } else {
      float delta = 10.0f / 255.0f;
      float idxf = rintf((x + 20.0f) * 25.5f);
      idxf = fminf(fmaxf(idxf, 0.0f), 255.0f);
      float xs = -20.0f + idxf * delta;
      e = rintf((float)exp((double)xs) / EXP_SCALE_F);
    }
    e = fminf(fmaxf(e, -32768.0f), 32767.0f);
    exp_tab[t] = (int)e;

    const float RECIP_SCALE_F = (float)((1.0 / 0.1) * 2.0 / 65535.0);
    float deltar = (250.0f - 0.1f) / 255.0f;
    float xs = 0.1f + (float)t * deltar;
    float r = rintf((1.0f / xs) / RECIP_SCALE_F);
    r = fminf(fmaxf(r, -32768.0f), 32767.0f);
    recip_tab[t] = r;
  }

  // ---- load 8 channels x 4 pixels; pack to 4x int8 per int; local max ----
  const int4* g4 = (const int4*)data;
  int pd[8];                         // packed raw data, 8 VGPRs
  int4 m = make_int4(-128, -128, -128, -128);
#pragma unroll
  for (int i = 0; i < 8; ++i) {
    int4 v = g4[base4 + (16 * i + k) * (NHW / 4) + p4];
    m.x = max(m.x, v.x); m.y = max(m.y, v.y);
    m.z = max(m.z, v.z); m.w = max(m.w, v.w);
    pd[i] = (v.x & 255) | ((v.y & 255) << 8) | ((v.z & 255) << 16) |
            (int)((unsigned)(v.w & 255) << 24);
  }
  red_m[k][p4] = m;
  __syncthreads();

  // ---- every thread reduces the 16 partial maxes (broadcast b128 reads) ----
  int4 q = red_m[0][p4];
#pragma unroll
  for (int kk = 1; kk < 16; ++kk) {
    int4 r = red_m[kk][p4];
    q.x = max(q.x, r.x); q.y = max(q.y, r.y);
    q.z = max(q.z, r.z); q.w = max(q.w, r.w);
  }

  // ---- exp LUT gather + pack exp (u16 pairs) + channel partial sum ----
  int pe[16];                        // packed exp, 16 VGPRs
  int4 s = make_int4(0, 0, 0, 0);
#pragma unroll
  for (int i = 0; i < 8; ++i) {
    int pdv = pd[i];
    int c0 = (pdv << 24) >> 24;
    int c1 = (pdv << 16) >> 24;
    int c2 = (pdv << 8) >> 24;
    int c3 = pdv >> 24;
    int e0 = exp_tab[q.x - c0];      // j guaranteed in [0,255]
    int e1 = exp_tab[q.y - c1];
    int e2 = exp_tab[q.z - c2];
    int e3 = exp_tab[q.w - c3];
    s.x += e0; s.y += e1; s.z += e2; s.w += e3;
    pe[2 * i]     = e0 | (e1 << 16); // e in [0,32767] -> fits u16, sign-safe
    pe[2 * i + 1] = e2 | (e3 << 16);
  }
  red_s[k][p4] = s;
  __syncthreads();

  // ---- every thread reduces the 16 partial sums, then recip (redundant) ----
  int4 tot = red_s[0][p4];
#pragma unroll
  for (int kk = 1; kk < 16; ++kk) {
    int4 r = red_s[kk][p4];
    tot.x += r.x; tot.y += r.y; tot.z += r.z; tot.w += r.w;
  }
  const float DIV_SCALE_F = (float)((2.0 / 65535.0) * 128.0); // exp_scale * 2^7
  const float RIDX_K_F    = (float)(255.0 / (250.0 - 0.1));
  float rq[4];
  {
    int tv[4] = {tot.x, tot.y, tot.z, tot.w};
#pragma unroll
    for (int j = 0; j < 4; ++j) {
      float ss = rintf((float)tv[j] * 0.0078125f);
      ss = fminf(fmaxf(ss, -32768.0f), 32767.0f);
      float v = ss * DIV_SCALE_F;
      float idxf = rintf((v - 0.1f) * RIDX_K_F);
      idxf = fminf(fmaxf(idxf, 0.0f), 255.0f);
      rq[j] = recip_tab[(int)idxf];
    }
  }

  // ---- epilogue: out = clip(round((e*r)*K), -128, 127) * OUT_SCALE ----
  const float K_F = (float)((2.0 / 65535.0) * ((1.0 / 0.1) * 2.0 / 65535.0) / (2.0 / 255.0));
  const float OUT_SCALE_F = (float)(2.0 / 255.0);
  vfloat4* o4 = (vfloat4*)out;
#pragma unroll
  for (int i = 0; i < 8; ++i) {
    int pa = pe[2 * i], pb = pe[2 * i + 1];
    float e0 = (float)(pa & 0xFFFF);
    float e1 = (float)(pa >> 16);
    float e2 = (float)(pb & 0xFFFF);
    float e3 = (float)(pb >> 16);
    vfloat4 o;
    o.x = fminf(fmaxf(rintf((e0 * rq[0]) * K_F), -128.0f), 127.0f) * OUT_SCALE_F;
    o.y = fminf(fmaxf(rintf((e1 * rq[1]) * K_F), -128.0f), 127.0f) * OUT_SCALE_F;
    o.z = fminf(fmaxf(rintf((e2 * rq[2]) * K_F), -128.0f), 127.0f) * OUT_SCALE_F;
    o.w = fminf(fmaxf(rintf((e3 * rq[3]) * K_F), -128.0f), 127.0f) * OUT_SCALE_F;
    __builtin_nontemporal_store(o, &o4[base4 + (16 * i + k) * (NHW / 4) + p4]);
  }
}

extern "C" void kernel_launch(void* const* d_in, const int* in_sizes, int n_in,
                              void* d_out, int out_size, void* d_ws, size_t ws_size,
                              hipStream_t stream) {
  const int* data     = (const int*)d_in[0];
  const float* dscale = (const float*)d_in[1];
  float* out          = (float*)d_out;
  (void)in_sizes; (void)n_in; (void)d_ws; (void)ws_size; (void)out_size;

  dim3 grid(NB * (NHW / PIX));   // 32 * 100 = 3200 blocks
  qsoftmax_kernel<<<grid, TPB, 0, stream>>>(data, dscale, out);
}